// Round 9
// baseline (99.164 us; speedup 1.0000x reference)
//
#include <hip/hip_runtime.h>
#include <hip/hip_bf16.h>

// ProductLayer: B=4096, F=32, D=64, U=256
// out[:,   0:256] = lz       = E[B,2048] @ W1[2048,256]
// out[:, 256:512] = lp_inner = G[B,1024] @ V [1024,256]   (G_b = E_b E_b^T gram)
// out[:, 512:768] = lp_outer = M[B,4096] @ W2[4096,256]   (M rank-1 from FS, generated)
// A = [E | G] bf16 [4096, 3072]; FS bf16 [4096,64]; Wt bf16 [256, 7168] (N-major)
// v9: m201-style 8-phase schedule. BM=256 BN=256 BK=64, 8 waves (2Mx4N, wave=128x64),
// 128 KB LDS dbuf, 224 uniform split-K blocks (16 mt x [4 seg0 + 2 seg1 + 8 seg2]
// chunks of K=512), 4 phases/K-step {stage||ds_read -> bar -> lgkm0 -> 16 MFMA
// (setprio) -> bar}, vmcnt(0) once per K-step. seg2 A generated in-phase from
// register-resident fs. Atomic fp32 epilogue into zeroed out.

#define KA 3072
#define KW 7168

typedef __attribute__((ext_vector_type(8))) short short8v;
typedef __attribute__((ext_vector_type(4))) float f32x4;

#define GLOAD(src, dst) __builtin_amdgcn_global_load_lds( \
    (const __attribute__((address_space(1))) void*)(src), \
    (__attribute__((address_space(3))) void*)(dst), 16, 0, 0)

static __device__ __forceinline__ short f2bf(float f) {
    union { float f; unsigned u; } v; v.f = f;
    unsigned r = v.u + 0x7fffu + ((v.u >> 16) & 1u);  // RNE
    return (short)(r >> 16);
}
static __device__ __forceinline__ float bf2f(short s) {
    union { unsigned u; float f; } v; v.u = ((unsigned)(unsigned short)s) << 16;
    return v.f;
}
static __device__ __forceinline__ int cvtpk(float lo, float hi) {
    int r;
    asm("v_cvt_pk_bf16_f32 %0, %1, %2" : "=v"(r) : "v"(lo), "v"(hi));
    return r;
}

// ---------------- zero out: 4096*768 floats = 786432 float4 ----------------
__global__ __launch_bounds__(256) void zero_out(float4* __restrict__ out) {
    size_t i = (size_t)blockIdx.x * 256 + threadIdx.x;
    #pragma unroll
    for (int r = 0; r < 3; ++r)
        out[i + (size_t)r * 262144] = (float4){0.f, 0.f, 0.f, 0.f};
}

// ---------------- prep: blocks 0-4095 = prep_a rows; 4096-4351 = prep_w units ----
__global__ __launch_bounds__(256) void prep(const float* __restrict__ embeds,
                                            const float* __restrict__ lw,
                                            const float* __restrict__ iw,
                                            const float* __restrict__ ow,
                                            short* __restrict__ A,
                                            short* __restrict__ FS,
                                            short* __restrict__ Wt) {
    __shared__ float se[2048];
    __shared__ short sebf[2048];
    int t = threadIdx.x;

    if (blockIdx.x < 4096) {
        int b = blockIdx.x;
        const float* e = embeds + (size_t)b * 2048;
        short* arow = A + (size_t)b * KA;

        float4 v0 = ((const float4*)e)[t * 2];
        float4 v1 = ((const float4*)e)[t * 2 + 1];
        ((float4*)se)[t * 2] = v0;
        ((float4*)se)[t * 2 + 1] = v1;
        short8v sb;
        sb[0] = f2bf(v0.x); sb[1] = f2bf(v0.y); sb[2] = f2bf(v0.z); sb[3] = f2bf(v0.w);
        sb[4] = f2bf(v1.x); sb[5] = f2bf(v1.y); sb[6] = f2bf(v1.z); sb[7] = f2bf(v1.w);
        ((short8v*)sebf)[t] = sb;
        *(short8v*)&arow[t * 8] = sb;   // E segment [0, 2048)

        __syncthreads();
        if (t < 64) {
            float s = 0.f;
            #pragma unroll
            for (int f = 0; f < 32; ++f) s += se[f * 64 + t];
            FS[(size_t)b * 64 + t] = f2bf(s);
        }

        // G = E E^T via MFMA: 4 waves, one 16x16 tile each, K=64 in 2 steps
        int wid = t >> 6, lane = t & 63;
        int tm = wid >> 1, tn = wid & 1;
        int lr = lane & 15, lk = (lane >> 4) * 8;
        f32x4 g = {0.f, 0.f, 0.f, 0.f};
        #pragma unroll
        for (int ks = 0; ks < 2; ++ks) {
            short8v a  = *(const short8v*)&sebf[(tm * 16 + lr) * 64 + ks * 32 + lk];
            short8v bb = *(const short8v*)&sebf[(tn * 16 + lr) * 64 + ks * 32 + lk];
            g = __builtin_amdgcn_mfma_f32_16x16x32_bf16(a, bb, g, 0, 0, 0);
        }
        #pragma unroll
        for (int r = 0; r < 4; ++r) {
            int grow = tm * 16 + (lane >> 4) * 4 + r;
            int gcol = tn * 16 + lr;
            arow[2048 + grow * 32 + gcol] = f2bf(g[r]);  // G segment [2048, 3072)
        }
    } else {
        int u = blockIdx.x - 4096;
        short* w = Wt + (size_t)u * KW;

        for (int k = t; k < 2048; k += 256) w[k] = f2bf(lw[(size_t)k * 256 + u]);

        if (t < 32) se[t] = iw[u * 32 + t];
        __syncthreads();
        for (int idx = t; idx < 1024; idx += 256)
            w[2048 + idx] = f2bf(se[idx >> 5] * se[idx & 31]);

        const float* owu = ow + (size_t)u * 4096;
        for (int i = t; i < 512; i += 256) {
            float4 a = ((const float4*)owu)[i * 2];
            float4 b = ((const float4*)owu)[i * 2 + 1];
            short8v s;
            s[0] = f2bf(a.x); s[1] = f2bf(a.y); s[2] = f2bf(a.z); s[3] = f2bf(a.w);
            s[4] = f2bf(b.x); s[5] = f2bf(b.y); s[6] = f2bf(b.z); s[7] = f2bf(b.w);
            *(short8v*)&w[3072 + i * 8] = s;
        }
    }
}

// One phase: [staging/gen issued by caller just before] ds_read subtile ->
// barrier -> lgkmcnt(0) -> 16 MFMA (setprio) -> [vmcnt(0) if K-step end] -> barrier
#define PHASE(CUR, KS, H, RB, LAST) do {                                            \
    int oct_ = (((KS) * 4 + hi) ^ (lr & 7)) * 8;                                    \
    short8v a_[4];                                                                  \
    _Pragma("unroll")                                                               \
    for (int m = 0; m < 4; ++m)                                                     \
        a_[m] = *(const short8v*)&As[CUR][(wm * 128 + ((H) * 4 + m) * 16 + lr) * 64 + oct_]; \
    if (RB) {                                                                       \
        _Pragma("unroll")                                                           \
        for (int n = 0; n < 4; ++n)                                                 \
            bfr[n] = *(const short8v*)&Bs[CUR][(wn * 64 + n * 16 + lr) * 64 + oct_];\
    }                                                                               \
    __builtin_amdgcn_s_barrier();                                                   \
    asm volatile("s_waitcnt lgkmcnt(0)" ::: "memory");                              \
    __builtin_amdgcn_sched_barrier(0);                                              \
    __builtin_amdgcn_s_setprio(1);                                                  \
    _Pragma("unroll")                                                               \
    for (int m = 0; m < 4; ++m)                                                     \
        _Pragma("unroll")                                                           \
        for (int n = 0; n < 4; ++n)                                                 \
            acc[(H) * 4 + m][n] = __builtin_amdgcn_mfma_f32_16x16x32_bf16(a_[m], bfr[n], acc[(H) * 4 + m][n], 0, 0, 0); \
    __builtin_amdgcn_s_setprio(0);                                                  \
    if (LAST) asm volatile("s_waitcnt vmcnt(0)" ::: "memory");                      \
    __builtin_amdgcn_s_barrier();                                                   \
} while (0)

// seg2 gen: one 8-elem slice of the rank-1 A-tile -> swizzled ds_write_b128
#define GEN(BUF, P, SVAL) do {                                                      \
    short8v fj_ = fsj[P];                                                           \
    union { int i32[4]; short8v v; } g_;                                            \
    _Pragma("unroll")                                                               \
    for (int q = 0; q < 4; ++q)                                                     \
        g_.i32[q] = cvtpk((SVAL) * bf2f(fj_[2 * q]), (SVAL) * bf2f(fj_[2 * q + 1]));\
    int jo_ = ((P) + jhalf * 4) ^ (grow & 7);                                       \
    *(short8v*)&As[BUF][grow * 64 + jo_ * 8] = g_.v;                                \
} while (0)

// ---------------- GEMM v9: 224 blocks x 512 threads (8 waves) ----------------
// id: mt = id/14, c = id%14. c 0-3: seg0 kc=c; 4-5: seg1 kc=c-4; 6-13: seg2 kc=c-6.
__global__ __launch_bounds__(512, 2) void gemm_tile(const short* __restrict__ A,
                                                    const short* __restrict__ Wt,
                                                    const short* __restrict__ FS,
                                                    float* __restrict__ out) {
    __shared__ short As[2][16384];   // 64 KB: A-tile dbuf [256 rows][64 k] swizzled
    __shared__ short Bs[2][16384];   // 64 KB: B-tile dbuf [256 cols][64 k] swizzled

    int id = blockIdx.x;
    int mt = id / 14, c = id % 14;
    int seg, kc;
    if (c < 4)      { seg = 0; kc = c; }
    else if (c < 6) { seg = 1; kc = c - 4; }
    else            { seg = 2; kc = c - 6; }
    int brow  = mt * 256;
    int akoff = (seg == 0) ? kc * 512 : 2048 + kc * 512;
    int boff  = (seg == 0) ? kc * 512 : (seg == 1) ? 2048 + kc * 512 : 3072 + kc * 512;

    int t = threadIdx.x, wid = t >> 6, lane = t & 63;
    int wm = wid >> 2, wn = wid & 3;           // wave tile: rows [wm*128,+128) x cols [wn*64,+64)
    int lr = lane & 15, hi = lane >> 4;
    int srow = t >> 3;                         // staging row 0..63 per issue
    int soct = (t & 7) ^ (srow & 7);           // pre-swizzled source octet (involution)

    const short* Asrc = A  + (size_t)(brow + srow) * KA + akoff + soct * 8;
    const short* Bsrc = Wt + (size_t)srow * KW + boff + soct * 8;

    auto stageA = [&](int p, int kt) {
        #pragma unroll
        for (int i = 0; i < 4; ++i)
            GLOAD(Asrc + (size_t)i * 64 * KA + kt * 64, &As[p][i * 4096 + t * 8]);
    };
    auto stageB = [&](int p, int kt) {
        #pragma unroll
        for (int i = 0; i < 4; ++i)
            GLOAD(Bsrc + (size_t)i * 64 * KW + kt * 64, &Bs[p][i * 4096 + t * 8]);
    };

    f32x4 acc[8][4];
    #pragma unroll
    for (int m = 0; m < 8; ++m)
        #pragma unroll
        for (int n = 0; n < 4; ++n) acc[m][n] = (f32x4){0.f, 0.f, 0.f, 0.f};
    short8v bfr[4];

    if (seg != 2) {
        stageA(0, 0); stageB(0, 0);
        __syncthreads();
        for (int kt = 0; kt < 8; ++kt) {
            int cur = kt & 1, nxt = cur ^ 1;
            bool st = kt < 7;
            if (st) stageA(nxt, kt + 1);
            PHASE(cur, 0, 0, true, false);
            if (st) stageB(nxt, kt + 1);
            PHASE(cur, 0, 1, false, false);
            PHASE(cur, 1, 0, true, false);
            PHASE(cur, 1, 1, false, true);
        }
    } else {
        // fs in registers: 2 threads per row; i-slice (8) + this thread's j-half (32)
        int grow = t >> 1, jhalf = t & 1;
        const short* fsrow = FS + (size_t)(brow + grow) * 64;
        short8v fsi = *(const short8v*)(fsrow + kc * 8);
        short8v fsj[4];
        #pragma unroll
        for (int q = 0; q < 4; ++q)
            fsj[q] = *(const short8v*)(fsrow + jhalf * 32 + q * 8);

        stageB(0, 0);
        {   // gen K-step 0 tile into As[0]
            float s0 = bf2f(fsi[0]);
            GEN(0, 0, s0); GEN(0, 1, s0); GEN(0, 2, s0); GEN(0, 3, s0);
        }
        __syncthreads();
        #pragma unroll
        for (int kt = 0; kt < 8; ++kt) {
            int cur = kt & 1, nxt = cur ^ 1;
            if (kt < 7) stageB(nxt, kt + 1);
            float sn = (kt < 7) ? bf2f(fsi[(kt + 1) & 7]) : 0.f;
            if (kt < 7) GEN(nxt, 0, sn);
            PHASE(cur, 0, 0, true, false);
            if (kt < 7) GEN(nxt, 1, sn);
            PHASE(cur, 0, 1, false, false);
            if (kt < 7) GEN(nxt, 2, sn);
            PHASE(cur, 1, 0, true, false);
            if (kt < 7) GEN(nxt, 3, sn);
            PHASE(cur, 1, 1, false, true);
        }
    }

    int segbase = seg * 256;
    #pragma unroll
    for (int m = 0; m < 8; ++m) {
        int row0 = brow + wm * 128 + m * 16 + hi * 4;
        #pragma unroll
        for (int n = 0; n < 4; ++n) {
            int col = segbase + wn * 64 + n * 16 + lr;
            #pragma unroll
            for (int r = 0; r < 4; ++r)
                unsafeAtomicAdd(&out[(size_t)(row0 + r) * 768 + col], acc[m][n][r]);
        }
    }
}

extern "C" void kernel_launch(void* const* d_in, const int* in_sizes, int n_in,
                              void* d_out, int out_size, void* d_ws, size_t ws_size,
                              hipStream_t stream) {
    const float* embeds = (const float*)d_in[0];
    const float* lw = (const float*)d_in[1];
    const float* iw = (const float*)d_in[2];
    const float* ow = (const float*)d_in[3];
    float* out = (float*)d_out;

    short* A  = (short*)d_ws;                    // 4096*3072*2 = 25,165,824 B
    short* Wt = A + (size_t)4096 * KA;           // + 256*7168*2 = 3,670,016 B
    short* FS = Wt + (size_t)256 * KW;           // + 4096*64*2 =    524,288 B

    zero_out<<<dim3(1024), dim3(256), 0, stream>>>((float4*)out);
    prep<<<dim3(4352), dim3(256), 0, stream>>>(embeds, lw, iw, ow, A, FS, Wt);
    gemm_tile<<<dim3(224), dim3(512), 0, stream>>>(A, Wt, FS, out);
}

// Round 10
// 62.673 us; speedup vs baseline: 1.5822x; 1.5822x over previous
//
#include <hip/hip_runtime.h>
#include <hip/hip_bf16.h>

// ProductLayer: B=4096, F=32, D=64, U=256
// out[:,   0:256] = lz       = E[B,2048] @ W1[2048,256]
// out[:, 256:512] = lp_inner = G[B,1024] @ V [1024,256]   (G_b = E_b E_b^T gram)
// out[:, 512:768] = lp_outer = M[B,4096] @ W2[4096,256]   (M rank-1 from FS, in-register)
// A = [E | G] bf16 [4096, 3072]; FS bf16 [4096,64]; Wt bf16 [256, 7168] (N-major)
// v10: v8's pipelined block (swizzle + counted vmcnt + setprio) x dense uniform grid:
// 896 blocks, ALL with exactly 16 K-steps (seg0: 2 chunks, seg1: 1, seg2: 4),
// depth-2 dbuf (24 KB LDS -> ~5 blocks/CU), XCD-bijective decode, atomic epilogue.

#define KA 3072
#define KW 7168

typedef __attribute__((ext_vector_type(8))) short short8v;
typedef __attribute__((ext_vector_type(4))) float f32x4;

#define GLOAD(src, dst) __builtin_amdgcn_global_load_lds( \
    (const __attribute__((address_space(1))) void*)(src), \
    (__attribute__((address_space(3))) void*)(dst), 16, 0, 0)

static __device__ __forceinline__ short f2bf(float f) {
    union { float f; unsigned u; } v; v.f = f;
    unsigned r = v.u + 0x7fffu + ((v.u >> 16) & 1u);  // RNE
    return (short)(r >> 16);
}
static __device__ __forceinline__ float bf2f(short s) {
    union { unsigned u; float f; } v; v.u = ((unsigned)(unsigned short)s) << 16;
    return v.f;
}
static __device__ __forceinline__ int cvtpk(float lo, float hi) {
    int r;
    asm("v_cvt_pk_bf16_f32 %0, %1, %2" : "=v"(r) : "v"(lo), "v"(hi));
    return r;
}

// ---------------- prep: 0-4095 prep_a rows; 4096-4351 prep_w; 4352-5375 zero out ----
__global__ __launch_bounds__(256) void prep(const float* __restrict__ embeds,
                                            const float* __restrict__ lw,
                                            const float* __restrict__ iw,
                                            const float* __restrict__ ow,
                                            short* __restrict__ A,
                                            short* __restrict__ FS,
                                            short* __restrict__ Wt,
                                            float4* __restrict__ outv) {
    __shared__ float se[2048];
    __shared__ short sebf[2048];
    int t = threadIdx.x;

    if (blockIdx.x >= 4352) {
        size_t i = (size_t)(blockIdx.x - 4352) * 256 + t;
        #pragma unroll
        for (int r = 0; r < 3; ++r)
            outv[i + (size_t)r * 262144] = (float4){0.f, 0.f, 0.f, 0.f};
        return;
    }

    if (blockIdx.x < 4096) {
        int b = blockIdx.x;
        const float* e = embeds + (size_t)b * 2048;
        short* arow = A + (size_t)b * KA;

        float4 v0 = ((const float4*)e)[t * 2];
        float4 v1 = ((const float4*)e)[t * 2 + 1];
        ((float4*)se)[t * 2] = v0;
        ((float4*)se)[t * 2 + 1] = v1;
        short8v sb;
        sb[0] = f2bf(v0.x); sb[1] = f2bf(v0.y); sb[2] = f2bf(v0.z); sb[3] = f2bf(v0.w);
        sb[4] = f2bf(v1.x); sb[5] = f2bf(v1.y); sb[6] = f2bf(v1.z); sb[7] = f2bf(v1.w);
        ((short8v*)sebf)[t] = sb;
        *(short8v*)&arow[t * 8] = sb;   // E segment [0, 2048)

        __syncthreads();
        if (t < 64) {
            float s = 0.f;
            #pragma unroll
            for (int f = 0; f < 32; ++f) s += se[f * 64 + t];
            FS[(size_t)b * 64 + t] = f2bf(s);
        }

        // G = E E^T via MFMA: 4 waves, one 16x16 tile each, K=64 in 2 steps
        int wid = t >> 6, lane = t & 63;
        int tm = wid >> 1, tn = wid & 1;
        int lr = lane & 15, lk = (lane >> 4) * 8;
        f32x4 g = {0.f, 0.f, 0.f, 0.f};
        #pragma unroll
        for (int ks = 0; ks < 2; ++ks) {
            short8v a  = *(const short8v*)&sebf[(tm * 16 + lr) * 64 + ks * 32 + lk];
            short8v bb = *(const short8v*)&sebf[(tn * 16 + lr) * 64 + ks * 32 + lk];
            g = __builtin_amdgcn_mfma_f32_16x16x32_bf16(a, bb, g, 0, 0, 0);
        }
        #pragma unroll
        for (int r = 0; r < 4; ++r) {
            int grow = tm * 16 + (lane >> 4) * 4 + r;
            int gcol = tn * 16 + lr;
            arow[2048 + grow * 32 + gcol] = f2bf(g[r]);  // G segment [2048, 3072)
        }
    } else {
        int u = blockIdx.x - 4096;
        short* w = Wt + (size_t)u * KW;

        for (int k = t; k < 2048; k += 256) w[k] = f2bf(lw[(size_t)k * 256 + u]);

        if (t < 32) se[t] = iw[u * 32 + t];
        __syncthreads();
        for (int idx = t; idx < 1024; idx += 256)
            w[2048 + idx] = f2bf(se[idx >> 5] * se[idx & 31]);

        const float* owu = ow + (size_t)u * 4096;
        for (int i = t; i < 512; i += 256) {
            float4 a = ((const float4*)owu)[i * 2];
            float4 b = ((const float4*)owu)[i * 2 + 1];
            short8v s;
            s[0] = f2bf(a.x); s[1] = f2bf(a.y); s[2] = f2bf(a.z); s[3] = f2bf(a.w);
            s[4] = f2bf(b.x); s[5] = f2bf(b.y); s[6] = f2bf(b.z); s[7] = f2bf(b.w);
            *(short8v*)&w[3072 + i * 8] = s;
        }
    }
}

// ---------------- GEMM v10: 896 uniform blocks, 16 K-steps each ----------------
// id: xcd = id&7, s = id>>3 (0..111); mtl = s&3, part = s>>2 (0..27);
// ck = part>>2 (0..6), nt = part&3; mt = xcd*4 + mtl.
// ck 0-1: seg0 kc=ck; ck 2: seg1; ck 3-6: seg2 kc=ck-3. All nk=16 (K-chunk 1024).
__global__ __launch_bounds__(256) void gemm_tile(const short* __restrict__ A,
                                                 const short* __restrict__ Wt,
                                                 const short* __restrict__ FS,
                                                 float* __restrict__ out) {
    __shared__ short As[2][8192];    // 16 KB dbuf (seg2: As[0] = fs tile 128x64)
    __shared__ short Bs[2][4096];    // 8 KB dbuf

    int id = blockIdx.x;
    int xcd = id & 7, s = id >> 3;
    int mtl = s & 3, part = s >> 2;
    int ck = part >> 2, nt = part & 3;
    int mt = xcd * 4 + mtl;
    int seg, kc;
    if (ck < 2)       { seg = 0; kc = ck; }
    else if (ck == 2) { seg = 1; kc = 0; }
    else              { seg = 2; kc = ck - 3; }
    const int nk = 16;
    int brow = mt * 128, bcol = nt * 64;
    int akoff = (seg == 0) ? kc * 1024 : 2048;
    int boff  = (seg == 0) ? kc * 1024 : (seg == 1) ? 2048 : 3072 + kc * 1024;

    int t = threadIdx.x, w = t >> 6, lane = t & 63;
    int lr = lane & 15, hi = lane >> 4;
    int srow = t >> 3;                       // staging row 0..31 per issue
    int soct = (t & 7) ^ (srow & 7);         // pre-swizzled source octet (involution)

    const short* Asrc = A  + (size_t)(brow + srow) * KA + akoff + soct * 8;
    const short* Bsrc = Wt + (size_t)(bcol + srow) * KW + boff  + soct * 8;
    const short* Fsrc = FS + (size_t)(brow + srow) * 64 + soct * 8;

    auto stageA = [&](int p, int kt) {
        #pragma unroll
        for (int i = 0; i < 4; ++i)
            GLOAD(Asrc + (size_t)i * 32 * KA + kt * 64, &As[p][i * 2048 + t * 8]);
    };
    auto stageB = [&](int p, int kt) {
        #pragma unroll
        for (int i = 0; i < 2; ++i)
            GLOAD(Bsrc + (size_t)i * 32 * KW + kt * 64, &Bs[p][i * 2048 + t * 8]);
    };

    f32x4 acc[2][4];
    #pragma unroll
    for (int m = 0; m < 2; ++m)
        #pragma unroll
        for (int n = 0; n < 4; ++n) acc[m][n] = (f32x4){0.f, 0.f, 0.f, 0.f};

    auto compute = [&](const short* a_s, const short* b_s) {
        #pragma unroll
        for (int ks = 0; ks < 2; ++ks) {
            int oct = ((ks * 4 + hi) ^ (lr & 7)) * 8;   // swizzled read octet
            short8v a[2], b[4];
            #pragma unroll
            for (int m = 0; m < 2; ++m)
                a[m] = *(const short8v*)&a_s[(w * 32 + m * 16 + lr) * 64 + oct];
            #pragma unroll
            for (int n = 0; n < 4; ++n)
                b[n] = *(const short8v*)&b_s[(n * 16 + lr) * 64 + oct];
            __builtin_amdgcn_s_setprio(1);
            #pragma unroll
            for (int m = 0; m < 2; ++m)
                #pragma unroll
                for (int n = 0; n < 4; ++n)
                    acc[m][n] = __builtin_amdgcn_mfma_f32_16x16x32_bf16(a[m], b[n], acc[m][n], 0, 0, 0);
            __builtin_amdgcn_s_setprio(0);
        }
    };

    if (seg != 2) {
        stageA(0, 0); stageB(0, 0);
        stageA(1, 1); stageB(1, 1);            // 12 loads in flight
        __builtin_amdgcn_sched_barrier(0);
        for (int kt = 0; kt < nk; ++kt) {
            int cur = kt & 1;
            if (kt + 1 < nk) asm volatile("s_waitcnt vmcnt(6)" ::: "memory");
            else             asm volatile("s_waitcnt vmcnt(0)" ::: "memory");
            __builtin_amdgcn_s_barrier();          // all waves' stage-kt landed
            __builtin_amdgcn_sched_barrier(0);
            compute(As[cur], Bs[cur]);
            __builtin_amdgcn_sched_barrier(0);
            __builtin_amdgcn_s_barrier();          // all waves done reading buf cur
            if (kt + 2 < nk) { stageA(cur, kt + 2); stageB(cur, kt + 2); }
            __builtin_amdgcn_sched_barrier(0);
        }
    } else {
        #pragma unroll
        for (int i = 0; i < 4; ++i)          // fs tile 128x64 -> As[0] (swizzled), once
            GLOAD(Fsrc + (size_t)i * 32 * 64, &As[0][i * 2048 + t * 8]);
        stageB(0, 0); stageB(1, 1);          // 4 + 4 loads in flight
        asm volatile("s_waitcnt vmcnt(4)" ::: "memory");   // fs landed
        __builtin_amdgcn_s_barrier();
        __builtin_amdgcn_sched_barrier(0);

        // preload the wave's fs j-octets (fixed per lane), f32
        float fj[2][2][8];
        #pragma unroll
        for (int m = 0; m < 2; ++m)
            #pragma unroll
            for (int ks = 0; ks < 2; ++ks) {
                int oct = ((ks * 4 + hi) ^ (lr & 7)) * 8;
                short8v v = *(const short8v*)&As[0][(w * 32 + m * 16 + lr) * 64 + oct];
                #pragma unroll
                for (int e = 0; e < 8; ++e) fj[m][ks][e] = bf2f(v[e]);
            }
        for (int kt = 0; kt < nk; ++kt) {
            int cur = kt & 1;
            if (kt + 1 < nk) asm volatile("s_waitcnt vmcnt(2)" ::: "memory");
            else             asm volatile("s_waitcnt vmcnt(0)" ::: "memory");
            __builtin_amdgcn_s_barrier();
            __builtin_amdgcn_sched_barrier(0);
            int iidx = kc * 16 + kt;                               // rank-1 col 0..63
            int ioff = ((iidx >> 3) ^ (lr & 7)) * 8 + (iidx & 7);  // swizzled
            float sv[2];
            #pragma unroll
            for (int m = 0; m < 2; ++m)
                sv[m] = bf2f(As[0][(w * 32 + m * 16 + lr) * 64 + ioff]);
            #pragma unroll
            for (int ks = 0; ks < 2; ++ks) {
                int oct = ((ks * 4 + hi) ^ (lr & 7)) * 8;
                short8v b[4];
                #pragma unroll
                for (int n = 0; n < 4; ++n)
                    b[n] = *(const short8v*)&Bs[cur][(n * 16 + lr) * 64 + oct];
                #pragma unroll
                for (int m = 0; m < 2; ++m) {
                    union { int i32[4]; short8v v; } fa;
                    #pragma unroll
                    for (int q2 = 0; q2 < 4; ++q2)
                        fa.i32[q2] = cvtpk(sv[m] * fj[m][ks][2 * q2], sv[m] * fj[m][ks][2 * q2 + 1]);
                    __builtin_amdgcn_s_setprio(1);
                    #pragma unroll
                    for (int n = 0; n < 4; ++n)
                        acc[m][n] = __builtin_amdgcn_mfma_f32_16x16x32_bf16(fa.v, b[n], acc[m][n], 0, 0, 0);
                    __builtin_amdgcn_s_setprio(0);
                }
            }
            __builtin_amdgcn_sched_barrier(0);
            __builtin_amdgcn_s_barrier();          // all waves done with Bs[cur]
            if (kt + 2 < nk) stageB(cur, kt + 2);
            __builtin_amdgcn_sched_barrier(0);
        }
    }

    int segbase = seg * 256;
    #pragma unroll
    for (int m = 0; m < 2; ++m) {
        int row0 = brow + w * 32 + m * 16 + hi * 4;
        #pragma unroll
        for (int n = 0; n < 4; ++n) {
            int col = segbase + bcol + n * 16 + lr;
            #pragma unroll
            for (int r = 0; r < 4; ++r)
                unsafeAtomicAdd(&out[(size_t)(row0 + r) * 768 + col], acc[m][n][r]);
        }
    }
}

extern "C" void kernel_launch(void* const* d_in, const int* in_sizes, int n_in,
                              void* d_out, int out_size, void* d_ws, size_t ws_size,
                              hipStream_t stream) {
    const float* embeds = (const float*)d_in[0];
    const float* lw = (const float*)d_in[1];
    const float* iw = (const float*)d_in[2];
    const float* ow = (const float*)d_in[3];
    float* out = (float*)d_out;

    short* A  = (short*)d_ws;                    // 4096*3072*2 = 25,165,824 B
    short* Wt = A + (size_t)4096 * KA;           // + 256*7168*2 = 3,670,016 B
    short* FS = Wt + (size_t)256 * KW;           // + 4096*64*2 =    524,288 B

    prep<<<dim3(5376), dim3(256), 0, stream>>>(embeds, lw, iw, ow, A, FS, Wt, (float4*)out);
    gemm_tile<<<dim3(896), dim3(256), 0, stream>>>(A, Wt, FS, out);
}

// Round 11
// 58.056 us; speedup vs baseline: 1.7081x; 1.0795x over previous
//
#include <hip/hip_runtime.h>
#include <hip/hip_bf16.h>

// ProductLayer: B=4096, F=32, D=64, U=256
// out[:,   0:256] = lz       = E[B,2048] @ W1[2048,256]
// out[:, 256:512] = lp_inner = G[B,1024] @ V [1024,256]   (G_b = E_b E_b^T gram)
// out[:, 512:768] = lp_outer = M[B,4096] @ W2[4096,256]   (M rank-1 from FST, in-register)
// A = [E | G] bf16 [4096, 3072]; FST bf16 [32][64][128] (fs transposed per 128-row
// group); Wt bf16 [256, 7168] (N-major).
// v11: m97 wave economics on the v10 pipeline. BM=128 BN=128 BK=64, 4 waves of
// 64x64 (16 MFMA per 8 ds_read_b128), 64 KB LDS dbuf (2 blocks/CU), 512 uniform
// blocks (all resident), XCD decode, swizzle, depth-2 counted vmcnt, setprio,
// atomic epilogue into out zeroed by prep.

#define KA 3072
#define KW 7168

typedef __attribute__((ext_vector_type(8))) short short8v;
typedef __attribute__((ext_vector_type(4))) float f32x4;

#define GLOAD(src, dst) __builtin_amdgcn_global_load_lds( \
    (const __attribute__((address_space(1))) void*)(src), \
    (__attribute__((address_space(3))) void*)(dst), 16, 0, 0)

static __device__ __forceinline__ short f2bf(float f) {
    union { float f; unsigned u; } v; v.f = f;
    unsigned r = v.u + 0x7fffu + ((v.u >> 16) & 1u);  // RNE
    return (short)(r >> 16);
}
static __device__ __forceinline__ float bf2f(short s) {
    union { unsigned u; float f; } v; v.u = ((unsigned)(unsigned short)s) << 16;
    return v.f;
}
static __device__ __forceinline__ int cvtpk(float lo, float hi) {
    int r;
    asm("v_cvt_pk_bf16_f32 %0, %1, %2" : "=v"(r) : "v"(lo), "v"(hi));
    return r;
}

// ---------------- prep: 0-4095 prep_a rows; 4096-4351 prep_w; 4352-5375 zero out ----
__global__ __launch_bounds__(256) void prep(const float* __restrict__ embeds,
                                            const float* __restrict__ lw,
                                            const float* __restrict__ iw,
                                            const float* __restrict__ ow,
                                            short* __restrict__ A,
                                            short* __restrict__ FST,
                                            short* __restrict__ Wt,
                                            float4* __restrict__ outv) {
    __shared__ float se[2048];
    __shared__ short sebf[2048];
    int t = threadIdx.x;

    if (blockIdx.x >= 4352) {
        size_t i = (size_t)(blockIdx.x - 4352) * 256 + t;
        #pragma unroll
        for (int r = 0; r < 3; ++r)
            outv[i + (size_t)r * 262144] = (float4){0.f, 0.f, 0.f, 0.f};
        return;
    }

    if (blockIdx.x < 4096) {
        int b = blockIdx.x;
        const float* e = embeds + (size_t)b * 2048;
        short* arow = A + (size_t)b * KA;

        float4 v0 = ((const float4*)e)[t * 2];
        float4 v1 = ((const float4*)e)[t * 2 + 1];
        ((float4*)se)[t * 2] = v0;
        ((float4*)se)[t * 2 + 1] = v1;
        short8v sb;
        sb[0] = f2bf(v0.x); sb[1] = f2bf(v0.y); sb[2] = f2bf(v0.z); sb[3] = f2bf(v0.w);
        sb[4] = f2bf(v1.x); sb[5] = f2bf(v1.y); sb[6] = f2bf(v1.z); sb[7] = f2bf(v1.w);
        ((short8v*)sebf)[t] = sb;
        *(short8v*)&arow[t * 8] = sb;   // E segment [0, 2048)

        __syncthreads();
        if (t < 64) {
            float s = 0.f;
            #pragma unroll
            for (int f = 0; f < 32; ++f) s += se[f * 64 + t];
            // transposed: FST[group b>>7][i = t][row-in-group b&127]
            FST[((size_t)(b >> 7)) * 8192 + t * 128 + (b & 127)] = f2bf(s);
        }

        // G = E E^T via MFMA: 4 waves, one 16x16 tile each, K=64 in 2 steps
        int wid = t >> 6, lane = t & 63;
        int tm = wid >> 1, tn = wid & 1;
        int lr = lane & 15, lk = (lane >> 4) * 8;
        f32x4 g = {0.f, 0.f, 0.f, 0.f};
        #pragma unroll
        for (int ks = 0; ks < 2; ++ks) {
            short8v a  = *(const short8v*)&sebf[(tm * 16 + lr) * 64 + ks * 32 + lk];
            short8v bb = *(const short8v*)&sebf[(tn * 16 + lr) * 64 + ks * 32 + lk];
            g = __builtin_amdgcn_mfma_f32_16x16x32_bf16(a, bb, g, 0, 0, 0);
        }
        #pragma unroll
        for (int r = 0; r < 4; ++r) {
            int grow = tm * 16 + (lane >> 4) * 4 + r;
            int gcol = tn * 16 + lr;
            arow[2048 + grow * 32 + gcol] = f2bf(g[r]);  // G segment [2048, 3072)
        }
    } else {
        int u = blockIdx.x - 4096;
        short* w = Wt + (size_t)u * KW;

        for (int k = t; k < 2048; k += 256) w[k] = f2bf(lw[(size_t)k * 256 + u]);

        if (t < 32) se[t] = iw[u * 32 + t];
        __syncthreads();
        for (int idx = t; idx < 1024; idx += 256)
            w[2048 + idx] = f2bf(se[idx >> 5] * se[idx & 31]);

        const float* owu = ow + (size_t)u * 4096;
        for (int i = t; i < 512; i += 256) {
            float4 a = ((const float4*)owu)[i * 2];
            float4 b = ((const float4*)owu)[i * 2 + 1];
            short8v s;
            s[0] = f2bf(a.x); s[1] = f2bf(a.y); s[2] = f2bf(a.z); s[3] = f2bf(a.w);
            s[4] = f2bf(b.x); s[5] = f2bf(b.y); s[6] = f2bf(b.z); s[7] = f2bf(b.w);
            *(short8v*)&w[3072 + i * 8] = s;
        }
    }
}

// ---------------- GEMM v11: 512 blocks x 4 waves (64x64 each), BM=BN=128 ----------------
// id: xcd = id&7, s = id>>3 (0..63); mt = xcd*4 + (s&3); sc = s>>2 (0..15);
// c = sc&7, nt = sc>>3. Chunks: c0-1 seg0 (nk=16), c2-3 seg1 (nk=8), c4-7 seg2 (nk=16).
__global__ __launch_bounds__(256, 2) void gemm_tile(const short* __restrict__ A,
                                                    const short* __restrict__ Wt,
                                                    const short* __restrict__ FST,
                                                    float* __restrict__ out) {
    __shared__ short As[2][8192];    // 16 KB each (seg2: As[0] = FST tile [64 j][128 row])
    __shared__ short Bs[2][8192];    // 16 KB each

    int id = blockIdx.x;
    int xcd = id & 7, s = id >> 3;
    int mt = xcd * 4 + (s & 3);
    int sc = s >> 2;
    int c = sc & 7, nt = sc >> 3;
    int seg, kc, nk;
    if (c < 2)      { seg = 0; kc = c;     nk = 16; }
    else if (c < 4) { seg = 1; kc = c - 2; nk = 8;  }
    else            { seg = 2; kc = c - 4; nk = 16; }
    int brow = mt * 128, bcol = nt * 128;
    int akoff = (seg == 0) ? kc * 1024 : 2048 + kc * 512;
    int boff  = (seg == 0) ? kc * 1024 : (seg == 1) ? 2048 + kc * 512 : 3072 + kc * 1024;

    int t = threadIdx.x, w = t >> 6, lane = t & 63;
    int wm = w >> 1, wn = w & 1;             // wave tile: rows [wm*64,+64) x cols [wn*64,+64)
    int lr = lane & 15, hi = lane >> 4;
    int srow = t >> 3;                       // staging row 0..31 per issue
    int soct = (t & 7) ^ (srow & 7);         // pre-swizzled source octet (involution)

    const short* Asrc = A  + (size_t)(brow + srow) * KA + akoff + soct * 8;
    const short* Bsrc = Wt + (size_t)(bcol + srow) * KW + boff  + soct * 8;
    const short* Fsrc = FST + (size_t)mt * 8192;   // linear tile, no swizzle

    auto stageA = [&](int p, int kt) {
        #pragma unroll
        for (int i = 0; i < 4; ++i)
            GLOAD(Asrc + (size_t)i * 32 * KA + kt * 64, &As[p][i * 2048 + t * 8]);
    };
    auto stageB = [&](int p, int kt) {
        #pragma unroll
        for (int i = 0; i < 4; ++i)
            GLOAD(Bsrc + (size_t)i * 32 * KW + kt * 64, &Bs[p][i * 2048 + t * 8]);
    };

    f32x4 acc[4][4];
    #pragma unroll
    for (int m = 0; m < 4; ++m)
        #pragma unroll
        for (int n = 0; n < 4; ++n) acc[m][n] = (f32x4){0.f, 0.f, 0.f, 0.f};

    auto compute = [&](const short* a_s, const short* b_s) {
        #pragma unroll
        for (int ks = 0; ks < 2; ++ks) {
            int oct = ((ks * 4 + hi) ^ (lr & 7)) * 8;   // swizzled read octet
            short8v a[4], b[4];
            #pragma unroll
            for (int m = 0; m < 4; ++m)
                a[m] = *(const short8v*)&a_s[(wm * 64 + m * 16 + lr) * 64 + oct];
            #pragma unroll
            for (int n = 0; n < 4; ++n)
                b[n] = *(const short8v*)&b_s[(wn * 64 + n * 16 + lr) * 64 + oct];
            __builtin_amdgcn_s_setprio(1);
            #pragma unroll
            for (int m = 0; m < 4; ++m)
                #pragma unroll
                for (int n = 0; n < 4; ++n)
                    acc[m][n] = __builtin_amdgcn_mfma_f32_16x16x32_bf16(a[m], b[n], acc[m][n], 0, 0, 0);
            __builtin_amdgcn_s_setprio(0);
        }
    };

    if (seg != 2) {
        stageA(0, 0); stageB(0, 0);
        stageA(1, 1); stageB(1, 1);            // 16 vm-ops in flight
        __builtin_amdgcn_sched_barrier(0);
        for (int kt = 0; kt < nk; ++kt) {
            int cur = kt & 1;
            if (kt + 1 < nk) asm volatile("s_waitcnt vmcnt(8)" ::: "memory");
            else             asm volatile("s_waitcnt vmcnt(0)" ::: "memory");
            __builtin_amdgcn_s_barrier();          // all waves' stage-kt landed
            __builtin_amdgcn_sched_barrier(0);
            compute(As[cur], Bs[cur]);
            __builtin_amdgcn_sched_barrier(0);
            __builtin_amdgcn_s_barrier();          // all waves done reading buf cur
            if (kt + 2 < nk) { stageA(cur, kt + 2); stageB(cur, kt + 2); }
            __builtin_amdgcn_sched_barrier(0);
        }
    } else {
        #pragma unroll
        for (int i = 0; i < 4; ++i)              // FST tile [64][128] -> As[0], linear
            GLOAD(Fsrc + i * 2048 + t * 8, &As[0][i * 2048 + t * 8]);
        stageB(0, 0); stageB(1, 1);              // 4 + 8 vm-ops in flight
        asm volatile("s_waitcnt vmcnt(8)" ::: "memory");   // FST landed
        __builtin_amdgcn_s_barrier();
        __builtin_amdgcn_sched_barrier(0);

        // fj[m][ks][e] = fs[row_m][(ks*4+hi)*8+e], conflict-free from transposed tile
        float fj[4][2][8];
        #pragma unroll
        for (int m = 0; m < 4; ++m) {
            int row = wm * 64 + m * 16 + lr;
            #pragma unroll
            for (int ks = 0; ks < 2; ++ks) {
                int j0 = (ks * 4 + hi) * 8;
                #pragma unroll
                for (int e = 0; e < 8; ++e)
                    fj[m][ks][e] = bf2f(As[0][(j0 + e) * 128 + row]);
            }
        }
        for (int kt = 0; kt < nk; ++kt) {
            int cur = kt & 1;
            if (kt + 1 < nk) asm volatile("s_waitcnt vmcnt(4)" ::: "memory");
            else             asm volatile("s_waitcnt vmcnt(0)" ::: "memory");
            __builtin_amdgcn_s_barrier();
            __builtin_amdgcn_sched_barrier(0);
            int iidx = kc * 16 + kt;             // rank-1 column index 0..63
            float sv[4];
            #pragma unroll
            for (int m = 0; m < 4; ++m)
                sv[m] = bf2f(As[0][iidx * 128 + wm * 64 + m * 16 + lr]);
            #pragma unroll
            for (int ks = 0; ks < 2; ++ks) {
                int oct = ((ks * 4 + hi) ^ (lr & 7)) * 8;
                short8v b[4];
                #pragma unroll
                for (int n = 0; n < 4; ++n)
                    b[n] = *(const short8v*)&Bs[cur][(wn * 64 + n * 16 + lr) * 64 + oct];
                #pragma unroll
                for (int m = 0; m < 4; ++m) {
                    union { int i32[4]; short8v v; } fa;
                    #pragma unroll
                    for (int q2 = 0; q2 < 4; ++q2)
                        fa.i32[q2] = cvtpk(sv[m] * fj[m][ks][2 * q2], sv[m] * fj[m][ks][2 * q2 + 1]);
                    __builtin_amdgcn_s_setprio(1);
                    #pragma unroll
                    for (int n = 0; n < 4; ++n)
                        acc[m][n] = __builtin_amdgcn_mfma_f32_16x16x32_bf16(fa.v, b[n], acc[m][n], 0, 0, 0);
                    __builtin_amdgcn_s_setprio(0);
                }
            }
            __builtin_amdgcn_sched_barrier(0);
            __builtin_amdgcn_s_barrier();          // all waves done with Bs[cur]
            if (kt + 2 < nk) stageB(cur, kt + 2);
            __builtin_amdgcn_sched_barrier(0);
        }
    }

    int segbase = seg * 256;
    #pragma unroll
    for (int m = 0; m < 4; ++m) {
        int row0 = brow + wm * 64 + m * 16 + hi * 4;
        #pragma unroll
        for (int n = 0; n < 4; ++n) {
            int col = segbase + bcol + wn * 64 + n * 16 + lr;
            #pragma unroll
            for (int r = 0; r < 4; ++r)
                unsafeAtomicAdd(&out[(size_t)(row0 + r) * 768 + col], acc[m][n][r]);
        }
    }
}

extern "C" void kernel_launch(void* const* d_in, const int* in_sizes, int n_in,
                              void* d_out, int out_size, void* d_ws, size_t ws_size,
                              hipStream_t stream) {
    const float* embeds = (const float*)d_in[0];
    const float* lw = (const float*)d_in[1];
    const float* iw = (const float*)d_in[2];
    const float* ow = (const float*)d_in[3];
    float* out = (float*)d_out;

    short* A   = (short*)d_ws;                    // 4096*3072*2 = 25,165,824 B
    short* Wt  = A + (size_t)4096 * KA;           // + 256*7168*2 = 3,670,016 B
    short* FST = Wt + (size_t)256 * KW;           // + 32*64*128*2 =   524,288 B

    prep<<<dim3(5376), dim3(256), 0, stream>>>(embeds, lw, iw, ow, A, FST, Wt, (float4*)out);
    gemm_tile<<<dim3(512), dim3(256), 0, stream>>>(A, Wt, FST, out);
}